// Round 5
// baseline (157.414 us; speedup 1.0000x reference)
//
#include <hip/hip_runtime.h>

#define HW   112
#define PH   114            // padded plane dim
#define KK   576
#define PLANE_SH (8 * PH * PH * 64)        // shorts per power plane
#define PLANE_B  (PLANE_SH * 2)            // bytes per plane
#define WB_OFF_SH (3 * PLANE_SH)
#define S_OFF_SH  (WB_OFF_SH + 36864)
// ws_size needed: ~40 MB

typedef __attribute__((ext_vector_type(8))) short s16x8;
typedef __attribute__((ext_vector_type(4))) float f32x4;
typedef __attribute__((ext_vector_type(2))) float f32x2;

__device__ inline unsigned short f2bf(float f) {
    unsigned u = __float_as_uint(f);
    u += 0x7FFF + ((u >> 16) & 1);            // RNE
    return (unsigned short)(u >> 16);
}

// ---- pass 1a: zero the 1-px borders of the three padded planes ----
__global__ void border_kernel(unsigned short* __restrict__ pw) {
    const int bid = blockIdx.x;              // 24 = 3p * 8b
    const int p = bid >> 3, b = bid & 7;
    unsigned short* base = pw + (size_t)p * PLANE_SH + (size_t)b * PH * PH * 64;
    const int t = threadIdx.x;
    const s16x8 z = {0, 0, 0, 0, 0, 0, 0, 0};
    for (int i = 0; i < 15; ++i) {
        const int e = t + i * 256;
        if (e >= 3616) break;                // 452 border px * 8 c-octs
        const int n = e >> 3, c8 = e & 7;
        int x, yy;
        if (n < 114)      { yy = 0;   x = n; }
        else if (n < 228) { yy = 113; x = n - 114; }
        else { const int m2 = n - 228; yy = 1 + (m2 >> 1); x = (m2 & 1) ? 113 : 0; }
        *(s16x8*)&base[(yy * PH + x) * 64 + c8 * 8] = z;
    }
}

// ---- pass 1b: NCHW fp32 -> padded NHWC bf16 planes of v, v^2, v^3 ----
__global__ __launch_bounds__(256) void pow_kernel(const float* __restrict__ img,
                                                  unsigned short* __restrict__ pw) {
    __shared__ __align__(16) unsigned short sA[3 * 112 * 72];   // [p][x][c pad 72]
    const int t = threadIdx.x;
    const int bid = blockIdx.x;              // 896 = 8b * 112y
    const int b = bid / 112, y = bid - b * 112;

    const int c = t & 63, xq0 = t >> 6;
    const float4* src = (const float4*)(img + (((size_t)(b * 64 + c) * HW + y) * HW));
    #pragma unroll
    for (int i = 0; i < 7; ++i) {
        const int xq = xq0 + i * 4;
        const float4 v = src[xq];
        const float vv[4] = {v.x, v.y, v.z, v.w};
        #pragma unroll
        for (int u = 0; u < 4; ++u) {
            const float v1 = vv[u], v2 = v1 * v1, v3 = v2 * v1;
            const int x = xq * 4 + u;
            sA[x * 72 + c]         = f2bf(v1);
            sA[8064 + x * 72 + c]  = f2bf(v2);
            sA[16128 + x * 72 + c] = f2bf(v3);
        }
    }
    __syncthreads();

    for (int i = 0; i < 11; ++i) {
        const int ch = t + i * 256;
        if (ch >= 2688) break;               // 3p * 112x * 8 c-octs
        const int p = ch / 896, r = ch - p * 896;
        const int x = r >> 3, c8 = r & 7;
        const s16x8 val = *(const s16x8*)&sA[p * 8064 + x * 72 + c8 * 8];
        *(s16x8*)&pw[(size_t)p * PLANE_SH + ((size_t)(b * PH + y + 1) * PH + (x + 1)) * 64 + c8 * 8] = val;
    }
}

// ---- pass 1c: weights -> bf16 MFMA-B fragment order + row sums ----
// Wb flat index: (((tap*2 + cc)*4 + nt)*64 + lane)*8 + j
//   k = cc*32 + (lane>>4)*8 + j, n = nt*16 + (lane&15), value = W[n][k*9 + tap]
__global__ void prep_kernel(const float* __restrict__ W,
                            unsigned short* __restrict__ wb,
                            float* __restrict__ S) {
    __shared__ float partial[256];
    const int bid = blockIdx.x, t = threadIdx.x;
    if (bid < 144) {
        const int i   = bid * 256 + t;
        const int j   = i & 7;
        const int l   = (i >> 3) & 63;
        const int nt  = (i >> 9) & 3;
        const int cc  = (i >> 11) & 1;
        const int tap = i >> 12;
        const int c   = cc * 32 + ((l >> 4) << 3) + j;
        const int o   = nt * 16 + (l & 15);
        wb[i] = f2bf(W[o * KK + c * 9 + tap]);
    } else {
        const int o = t >> 2, part = t & 3;
        const float4* row = (const float4*)(W + o * KK) + part * 36;
        float s = 0.f;
        for (int k = 0; k < 36; ++k) { float4 v = row[k]; s += v.x + v.y + v.z + v.w; }
        partial[t] = s;
        __syncthreads();
        if (part == 0) S[o] = partial[t] + partial[t + 1] + partial[t + 2] + partial[t + 3];
    }
}

// ---- pass 2: implicit-GEMM conv, direct global->register, oc-split waves ----
// wave = 2 rows x 16 px x 32 oc: rowg = wv&1 (row pair), ocg = wv>>1 (oc half)
__global__ __launch_bounds__(256, 3) void conv_main(const unsigned short* __restrict__ pw,
                                                    const unsigned short* __restrict__ wb,
                                                    const float* __restrict__ S,
                                                    float* __restrict__ out) {
    const int t = threadIdx.x, wv = t >> 6, lane = t & 63;
    const int m = lane & 15, q = lane >> 4;
    const int rowg = wv & 1, ocg = wv >> 1;

    const int bid = blockIdx.x;       // 1568: b = bid&7 (XCD/L2 affinity)
    const int b = bid & 7;
    const int r = bid >> 3;           // 0..195 = 28 ty * 7 tx
    const int ty = r / 7, tx = r - ty * 7;
    const int Y0 = ty * 4 + rowg * 2; // this wave's output rows: Y0, Y0+1
    const int X0 = tx * 16;

    f32x4 acc[3][2][2];               // [power][at][ntl]
    #pragma unroll
    for (int p = 0; p < 3; ++p)
        #pragma unroll
        for (int at = 0; at < 2; ++at)
            #pragma unroll
            for (int ntl = 0; ntl < 2; ++ntl)
                acc[p][at][ntl] = (f32x4){0.f, 0.f, 0.f, 0.f};

    const char* pb = (const char*)(pw + (size_t)b * PH * PH * 64);
    int vofs[4];
    #pragma unroll
    for (int r4 = 0; r4 < 4; ++r4)
        vofs[r4] = ((Y0 + r4) * PH + X0 + m) * 128 + q * 16;   // padded row Y0+r4 serves (at,ky): at+ky==r4

    #pragma unroll
    for (int cc = 0; cc < 2; ++cc) {
        #pragma unroll
        for (int kx = 0; kx < 3; ++kx) {
            // B fragments for this wave's 2 oc-groups (lane-linear 1KB, L1/L2-resident)
            s16x8 bf[3][2];
            #pragma unroll
            for (int ky = 0; ky < 3; ++ky) {
                const int tap = ky * 3 + kx;
                #pragma unroll
                for (int ntl = 0; ntl < 2; ++ntl)
                    bf[ky][ntl] = *(const s16x8*)&wb[(((tap * 2 + cc) * 4 + (ocg * 2 + ntl)) * 64 + lane) * 8];
            }
            // A fragments: 4 rows x 3 powers, contiguous 16B each
            s16x8 af[4][3];
            #pragma unroll
            for (int r4 = 0; r4 < 4; ++r4)
                #pragma unroll
                for (int p = 0; p < 3; ++p)
                    af[r4][p] = *(const s16x8*)(pb + (size_t)p * PLANE_B
                                                + vofs[r4] + kx * 128 + cc * 64);
            // 36 MFMA
            #pragma unroll
            for (int ky = 0; ky < 3; ++ky)
                #pragma unroll
                for (int at = 0; at < 2; ++at)
                    #pragma unroll
                    for (int p = 0; p < 3; ++p)
                        #pragma unroll
                        for (int ntl = 0; ntl < 2; ++ntl)
                            acc[p][at][ntl] = __builtin_amdgcn_mfma_f32_16x16x32_bf16(
                                af[at + ky][p], bf[ky][ntl], acc[p][at][ntl], 0, 0, 0);
        }
    }

    // ---- epilogue: telescoped diffs + float2 packed math (v_pk_fma_f32) ----
    // D layout: n = lane&15, pixel m' = q*4 + reg
    #pragma unroll
    for (int ntl = 0; ntl < 2; ++ntl) {
        const int o = (ocg * 2 + ntl) * 16 + (lane & 15);
        const float Sv = S[o];
        const float fS = -0.000287f / 75.f * Sv;
        const float cg1 = 0.8448f  + 0.001309f * Sv;
        const float D1  = 0.52992f - 0.003809f * Sv;
        const float D2  = 0.45312f + 0.001546f * Sv;
        const float D3  = 1.152f   - 0.006386f * Sv;
        const float D4  = 0.91392f - 0.00283f  * Sv;
        #pragma unroll
        for (int at = 0; at < 2; ++at) {
            float res[4];
            #pragma unroll
            for (int h = 0; h < 2; ++h) {     // pairs (rg 2h, 2h+1)
                const f32x2 u1 = {acc[0][at][ntl][2 * h], acc[0][at][ntl][2 * h + 1]};
                const f32x2 u2 = {acc[1][at][ntl][2 * h], acc[1][at][ntl][2 * h + 1]};
                const f32x2 u3 = {acc[2][at][ntl][2 * h], acc[2][at][ntl][2 * h + 1]};
                const f32x2 f  = fS   + 0.00354667f * u1 - 0.00146267f * u2;
                const f32x2 g1 = cg1  + 0.00619f    * u1 - 0.009f      * u2 + 0.001383f * u3;
                const f32x2 d1 = D1   - 0.00316f    * u1 + 0.00416f    * u2 + 0.016117f * u3;
                const f32x2 d2 = D2   - 0.00116f    * u1 + 0.006717f   * u2 - 0.00248f  * u3;
                const f32x2 d3 = D3   - 0.000753f   * u1 + 0.005643f   * u2 - 0.00602f  * u3;
                const f32x2 d4 = D4   - 0.000691f   * u1 + 0.00085f    * u2 - 0.00487f  * u3;
                f32x2 E;
                E.x = __expf(-10.f * f.x);
                E.y = __expf(-10.f * f.y);
                const f32x2 den1 = 1.f + E * 4.4816890703f;
                const f32x2 den2 = 1.f + E * 9.9741824548f;
                const f32x2 den3 = 1.f + E * 24.5325301971f;
                const f32x2 den4 = 1.f + E * 49.4024491055f;
                f32x2 o2 = g1;
                o2.x += __builtin_amdgcn_rcpf(den1.x) * d1.x + __builtin_amdgcn_rcpf(den2.x) * d2.x
                      + __builtin_amdgcn_rcpf(den3.x) * d3.x + __builtin_amdgcn_rcpf(den4.x) * d4.x;
                o2.y += __builtin_amdgcn_rcpf(den1.y) * d1.y + __builtin_amdgcn_rcpf(den2.y) * d2.y
                      + __builtin_amdgcn_rcpf(den3.y) * d3.y + __builtin_amdgcn_rcpf(den4.y) * d4.y;
                res[2 * h] = o2.x; res[2 * h + 1] = o2.y;
            }
            const int y = Y0 + at;
            float* op = out + (((size_t)(b * 64 + o)) * HW + y) * HW + X0 + q * 4;
            *(float4*)op = make_float4(res[0], res[1], res[2], res[3]);
        }
    }
}

extern "C" void kernel_launch(void* const* d_in, const int* in_sizes, int n_in,
                              void* d_out, int out_size, void* d_ws, size_t ws_size,
                              hipStream_t stream) {
    const float* img = (const float*)d_in[0];
    const float* w   = (const float*)d_in[1];
    float* outp = (float*)d_out;
    unsigned short* pw = (unsigned short*)d_ws;
    unsigned short* wb = pw + WB_OFF_SH;
    float* S = (float*)(pw + S_OFF_SH);

    hipLaunchKernelGGL(border_kernel, dim3(24),   dim3(256), 0, stream, pw);
    hipLaunchKernelGGL(pow_kernel,    dim3(896),  dim3(256), 0, stream, img, pw);
    hipLaunchKernelGGL(prep_kernel,   dim3(145),  dim3(256), 0, stream, w, wb, S);
    hipLaunchKernelGGL(conv_main,     dim3(1568), dim3(256), 0, stream, pw, wb, S, outp);
}